// Round 12
// baseline (1233.524 us; speedup 1.0000x reference)
//
#include <hip/hip_runtime.h>
#include <stdint.h>

// W4A16 dequant-GEMM for MI355X (gfx950) — B-direct-to-register round.
// Dtypes (fp16 ref normalized by harness): X f32[8192][4096], W int32[11008][2048]
// (one byte = 2 int4 per element), S f32[11008][32], Y f32[8192][11008].
//
// Fast path: cvt_x (X->bf16) + cvt_w (dequant W->bf16) into d_ws, then bf16 GEMM:
// 256x256 tile, BK=64, 512 thr = 8 waves (2M x 4N), 128x64 out/wave (acc[8][4]).
// R11 post-mortem: every schedule variant sat at 50% MfmaUtil == serialized
// LDS(2304cy) + MFMA(2483cy) per tile: MFMA issue-stall blocks the wave, and
// barriered ds_reads can't issue during it. Fix: B fragments bypass LDS --
// loaded global->VGPR (VMEM pipe, runs under MFMA issue-stall), prefetched one
// K-tile ahead into a parity double-set. A stays global_load_lds-staged in a
// ring-4 of 32KB slots (stage t+2 vs read t: never same/adjacent slot). One
// barrier pair per tile; A reads split in two 8-read bursts hidden under the
// two quadrant-pair MFMA windows. One counted gate per tile (GATE20 steady,
// counts 8 B-loads + 4 A-stages per tile), gate->barrier->read discipline.
// Fallback (ws too small): fused single-buffer kernel (round-3-verified algebra).

namespace {

typedef unsigned int u32;
typedef unsigned short u16;
typedef __attribute__((ext_vector_type(8))) short bf16x8;   // 8 bf16 = 4 VGPR
typedef __attribute__((ext_vector_type(4))) float f32x4;
typedef __attribute__((ext_vector_type(4))) u32 u32x4;

constexpr int Mt = 8192;
constexpr int Nt = 11008;
constexpr int Kt = 4096;
constexpr int KP = Kt / 2;     // int32 per W row
constexpr int NG = 32;         // scale groups
constexpr int BM = 256;
constexpr int BN = 256;
constexpr int BK = 64;
constexpr int THREADS = 512;
constexpr int GRID = (Mt / BM) * (Nt / BN);   // 32*43 = 1376 (div by 8)
constexpr int NKT = Kt / BK;                  // 64 K-tiles
constexpr int NB_CNT = Nt / BN;               // 43

__device__ __forceinline__ u16 f2bf(float f) {   // RNE f32 -> bf16 bits
  u32 u = __float_as_uint(f);
  return (u16)((u + 0x7FFFu + ((u >> 16) & 1u)) >> 16);
}
__device__ __forceinline__ u32 pk2bf(float a, float b) {
  return (u32)f2bf(a) | ((u32)f2bf(b) << 16);
}
__device__ __forceinline__ u32 dqpair(u32 b, float s, float c) {
  float f0 = (float)(b & 15u);
  float f1 = (float)((b >> 4) & 15u);
  return pk2bf(fmaf(f0, s, c), fmaf(f1, s, c));
}
__device__ __forceinline__ void async16(const void* g, void* l) {
  __builtin_amdgcn_global_load_lds(
      (const __attribute__((address_space(1))) u32*)g,
      (__attribute__((address_space(3))) u32*)l, 16, 0, 0);
}

// ---- one-shot converters (HBM-bound, ~60 us total) ----
__global__ __launch_bounds__(256) void cvt_x(const float* __restrict__ X,
                                             u32* __restrict__ O) {
  const int total = Mt * Kt / 4;
  for (int j = blockIdx.x * 256 + threadIdx.x; j < total;
       j += (int)(gridDim.x * 256)) {
    float4 v = ((const float4*)X)[j];
    ((uint2*)O)[j] = make_uint2(pk2bf(v.x, v.y), pk2bf(v.z, v.w));
  }
}

__global__ __launch_bounds__(256) void cvt_w(const int* __restrict__ W,
                                             const float* __restrict__ S,
                                             u32* __restrict__ O) {
  const int total = Nt * KP / 4;
  for (int j = blockIdx.x * 256 + threadIdx.x; j < total;
       j += (int)(gridDim.x * 256)) {
    int4 v = ((const int4*)W)[j];
    int vv[4] = {v.x, v.y, v.z, v.w};
    const int j0 = j * 4;            // flat int32 index = row*2048 + jj
    const int row = j0 >> 11;
    const int jj = j0 & 2047;
    const float* sr = S + (size_t)row * NG;
    u32x4 o;
    #pragma unroll
    for (int e = 0; e < 4; ++e) {
      float s = sr[(jj + e) >> 6];   // group = (2*jj)/128 = jj/64
      o[e] = dqpair((u32)vv[e], s, -8.f * s);
    }
    ((u32x4*)O)[j] = o;              // u32 idx jj holds k=2jj (lo), 2jj+1 (hi)
  }
}

// ---- main GEMM: 256x256, BK=64, A via LDS ring-4, B direct-to-reg ----
__global__ __launch_bounds__(THREADS, 2) void gemmbr(
    const u16* __restrict__ Xb, const u16* __restrict__ Wb,
    float* __restrict__ Y) {
  // A ring: 4 slots x 32KB (rows 0..255 x 128B, XOR-swizzled 16B slots).
  __shared__ __align__(16) unsigned char smem[4 * 32768];

  const int tid  = (int)threadIdx.x;
  const int lane = tid & 63;
  const int wid  = tid >> 6;   // 0..7
  const int wm   = wid >> 2;   // 0..1  (M dir, 128 rows/wave)
  const int wn   = wid & 3;    // 0..3  (N dir, 64 cols/wave)

  // XCD-bijective swizzle (1376 = 8*172); nb fast-varying.
  const int bid = (int)blockIdx.x;
  const int wg  = (bid & 7) * (GRID / 8) + (bid >> 3);
  const int mb  = wg / NB_CNT;
  const int nb  = wg - mb * NB_CNT;
  const int m0  = mb * BM;
  const int n0  = nb * BN;

  // ---- A staging: slot = rows 0..255, row r at r*128 B; per thread 4 x 16B
  // (rows srow + i*64). Physical 16B-slot = logical ^ (row&7); source
  // pre-swizzled so LDS dest is linear (issue i at slot + i*8192 + tid*16).
  const int srow = tid >> 3;                       // 0..63
  const int sswz = (tid & 7) ^ (srow & 7);         // logical source slot
  const u16* aRow = Xb + (size_t)(m0 + srow) * Kt + sswz * 8;
  const int ldst = tid * 16;

  // ---- A fragment-read constants ----
  // af[q][kk]: global row = wm*128 + fg*64 + q*16 + frow; byte in row:
  // slot = (kk*4+fk) ^ (row&7), row&7 == lane&7.
  const int frow = lane & 15;
  const int fk   = lane >> 4;                 // 0..3
  const int s0o  = ((fk ^ (lane & 7)) << 4);        // kk=0 slot byte
  const int s1o  = (((4 + fk) ^ (lane & 7)) << 4);  // kk=1 slot byte

  // ---- B fragment global base: row = n0 + wn*64 + fn*16 + frow, k-chunk fk.
  const u16* wB = Wb + (size_t)(n0 + wn * 64 + frow) * Kt + fk * 8;

  f32x4 acc[8][4];
  #pragma unroll
  for (int i = 0; i < 8; ++i)
    #pragma unroll
    for (int j = 0; j < 4; ++j) acc[i][j] = f32x4{0.f, 0.f, 0.f, 0.f};

  #define GATE(n) asm volatile("s_waitcnt vmcnt(" #n ")" ::: "memory")
  #define BARR()  asm volatile("s_barrier" ::: "memory")

  // Stage full A tile kt into ring slot (4 x global_load_lds per thread).
  #define STAGE_A(SLOT, KT)                                                    \
    do {                                                                       \
      unsigned char* d_ = smem + (SLOT) * 32768 + ldst;                        \
      const u16* s_ = aRow + (KT) * 64;                                        \
      async16(s_, d_);                                                         \
      async16(s_ + (size_t)64 * Kt, d_ + 8192);                                \
      async16(s_ + (size_t)128 * Kt, d_ + 16384);                              \
      async16(s_ + (size_t)192 * Kt, d_ + 24576);                              \
    } while (0)

  // Read A fragments of half FG (8 x ds_read_b128) from ring slot.
  #define LD_A(FG, SLOT)                                                       \
    do {                                                                       \
      const unsigned char* b_ =                                                \
          smem + (SLOT) * 32768 + (wm * 128 + (FG) * 64 + frow) * 128;         \
      _Pragma("unroll")                                                        \
      for (int q_ = 0; q_ < 4; ++q_) {                                         \
        af[q_][0] = *(const bf16x8*)(b_ + q_ * 2048 + s0o);                    \
        af[q_][1] = *(const bf16x8*)(b_ + q_ * 2048 + s1o);                    \
      }                                                                        \
    } while (0)

  // Load B fragment set for K-tile KT (8 x global_load_dwordx4, 16B aligned).
  #define LOADB(DST, KT)                                                       \
    do {                                                                       \
      _Pragma("unroll")                                                        \
      for (int fn_ = 0; fn_ < 4; ++fn_) {                                      \
        _Pragma("unroll")                                                      \
        for (int kk_ = 0; kk_ < 2; ++kk_)                                      \
          DST[fn_][kk_] = *(const bf16x8*)(wB + (size_t)fn_ * 16 * Kt +        \
                                           (KT) * 64 + kk_ * 32);              \
      }                                                                        \
    } while (0)

  // One C-quadrant (16 MFMA) with B register set BS.
  #define MMQ(FG, FNP, BS)                                                     \
    do {                                                                       \
      __builtin_amdgcn_s_setprio(1);                                           \
      _Pragma("unroll")                                                        \
      for (int q_ = 0; q_ < 4; ++q_)                                           \
        _Pragma("unroll")                                                      \
        for (int fn_ = 0; fn_ < 2; ++fn_)                                      \
          _Pragma("unroll")                                                    \
          for (int kk_ = 0; kk_ < 2; ++kk_)                                    \
            acc[(FG) * 4 + q_][(FNP) * 2 + fn_] =                              \
                __builtin_amdgcn_mfma_f32_16x16x32_bf16(                       \
                    af[q_][kk_], BS[(FNP) * 2 + fn_][kk_],                     \
                    acc[(FG) * 4 + q_][(FNP) * 2 + fn_], 0, 0, 0);             \
      __builtin_amdgcn_s_setprio(0);                                           \
    } while (0)

  // One K-tile: pre-region {af half0 reads, stage A(t+2), load B(t+1)} ->
  // BAR -> quadrants (0,*) -> af half1 reads -> quadrants (1,*) -> gate -> BAR.
  #define TILE(SLOT, SSLOT, BC, BN_, T, GATESTMT, DOSTAGE, DOB)                \
    do {                                                                       \
      LD_A(0, SLOT);                                                           \
      if (DOSTAGE) STAGE_A(SSLOT, (T) + 2);                                    \
      if (DOB) LOADB(BN_, (T) + 1);                                            \
      BARR();                                                                  \
      MMQ(0, 0, BC);                                                           \
      MMQ(0, 1, BC);                                                           \
      __builtin_amdgcn_sched_barrier(0);                                       \
      LD_A(1, SLOT);                                                           \
      MMQ(1, 0, BC);                                                           \
      MMQ(1, 1, BC);                                                           \
      GATESTMT;                                                                \
      BARR();                                                                  \
    } while (0)

  bf16x8 af[4][2];
  bf16x8 bs0[4][2], bs1[4][2];

  // Prologue: A(0)->slot0, A(1)->slot1 (8 DMA), B(0)->set0 (8 loads).
  STAGE_A(0, 0);
  STAGE_A(1, 1);
  LOADB(bs0, 0);
  GATE(12);           // A(0) landed (newer: A(1) x4 + B(0) x8 = 12)
  BARR();

  // Steady: tiles 0..59, unrolled x4 (slot = t&3, B set = t&1, all literal).
  // Per tile issues: 4 A-stage DMA + 8 B loads. Steady gate: A(t+1) landed
  // when <= B(t)x8 + A(t+2)x4 + B(t+1)x8 = 20 outstanding.
  #pragma unroll 1
  for (int t0 = 0; t0 < 60; t0 += 4) {
    TILE(0, 2, bs0, bs1, t0,     GATE(20), 1, 1);
    TILE(1, 3, bs1, bs0, t0 + 1, GATE(20), 1, 1);
    TILE(2, 0, bs0, bs1, t0 + 2, GATE(20), 1, 1);
    TILE(3, 1, bs1, bs0, t0 + 3, GATE(20), 1, 1);
  }
  // t=60, 61: steady shape (stage A(62), A(63)).
  TILE(0, 2, bs0, bs1, 60, GATE(20), 1, 1);
  TILE(1, 3, bs1, bs0, 61, GATE(20), 1, 1);
  // t=62: no A(64) stage; load B(63). Gate: A(63) newer = B(62)x8 + B(63)x8.
  TILE(2, 0, bs0, bs1, 62, GATE(16), 0, 1);
  // t=63: nothing staged/loaded; no trailing barrier needed.
  {
    LD_A(0, 3);
    BARR();
    MMQ(0, 0, bs1);
    MMQ(0, 1, bs1);
    __builtin_amdgcn_sched_barrier(0);
    LD_A(1, 3);
    MMQ(1, 0, bs1);
    MMQ(1, 1, bs1);
  }

  #undef GATE
  #undef BARR
  #undef STAGE_A
  #undef LD_A
  #undef LOADB
  #undef MMQ
  #undef TILE

  // Epilogue: C/D mapping col = lane&15, row = (lane>>4)*4 + reg (m89/m91).
  #pragma unroll
  for (int fm = 0; fm < 8; ++fm) {
    #pragma unroll
    for (int r = 0; r < 4; ++r) {
      const size_t mrow = (size_t)(m0 + wm * 128 + fm * 16 + fk * 4 + r) * Nt;
      #pragma unroll
      for (int fn = 0; fn < 4; ++fn) {
        Y[mrow + (size_t)(n0 + wn * 64 + fn * 16 + frow)] = acc[fm][fn][r];
      }
    }
  }
}

// ---- fallback: fused single-buffer kernel (round-3 verified algebra) ----
__global__ __launch_bounds__(512) void gemm_fused(
    const float* __restrict__ Xf, const int* __restrict__ W,
    const float* __restrict__ S, float* __restrict__ Y) {
  constexpr int FBN = 128;
  constexpr int FNB = Nt / FBN;   // 86
  constexpr int FBK = 64;
  constexpr int FNKT = Kt / FBK;
  __shared__ __align__(16) unsigned char Alds[BM * FBK * 2];
  __shared__ __align__(16) unsigned char Blds[FBN * FBK * 2];

  const int tid = (int)threadIdx.x;
  const int lane = tid & 63;
  const int wid = tid >> 6;
  const int wm = wid >> 1;
  const int wn = wid & 1;

  const int bid = (int)blockIdx.x;
  const int fgrid = (Mt / BM) * FNB;
  const int wg = (bid & 7) * (fgrid / 8) + (bid >> 3);
  const int mb = wg / FNB;
  const int nb = wg - mb * FNB;
  const int m0 = mb * BM;
  const int n0 = nb * FBN;

  const int frow = lane & 15;
  const int fk = lane >> 4;
  const int fswz = (lane & 7) << 4;
  const unsigned char* aRd = Alds + (wm * 64 + frow) * 128;
  const unsigned char* bRd = Blds + (wn * 64 + frow) * 128;

  f32x4 acc[4][4];
  #pragma unroll
  for (int i = 0; i < 4; ++i)
    #pragma unroll
    for (int j = 0; j < 4; ++j) acc[i][j] = f32x4{0.f, 0.f, 0.f, 0.f};

  const int arow = tid >> 3, acol = tid & 7;
  const float* fA = Xf + (size_t)(m0 + arow) * Kt + acol * 8;
  unsigned char* fAD = Alds + arow * 128 + ((acol ^ (arow & 7)) << 4);
  const int nloc = tid >> 3, c4 = tid & 7;
  const int* fB0 = W + (size_t)(n0 + nloc) * KP + c4 * 4;
  const int* fB1 = fB0 + (size_t)64 * KP;
  const float* sp0 = S + (size_t)(n0 + nloc) * NG;
  const float* sp1 = sp0 + (size_t)64 * NG;
  unsigned char* fBD0 = Blds + nloc * 128 + ((c4 ^ (nloc & 7)) << 4);
  unsigned char* fBD1 = fBD0 + 64 * 128;

  #pragma unroll 1
  for (int kt = 0; kt < FNKT; ++kt) {
    const int k0 = kt * FBK;
    #pragma unroll
    for (int p = 0; p < 4; ++p) {
      float4 x0 = *(const float4*)(fA + (size_t)p * 64 * Kt + k0);
      float4 x1 = *(const float4*)(fA + (size_t)p * 64 * Kt + k0 + 4);
      u32x4 q;
      q[0] = pk2bf(x0.x, x0.y); q[1] = pk2bf(x0.z, x0.w);
      q[2] = pk2bf(x1.x, x1.y); q[3] = pk2bf(x1.z, x1.w);
      *(u32x4*)(fAD + p * 64 * 128) = q;
    }
    const int g = k0 >> 7;
    const float s0 = sp0[g], s1 = sp1[g];
    const float c0 = -8.f * s0, c1 = -8.f * s1;
    const int4 w0 = *(const int4*)(fB0 + (k0 >> 1));
    const int4 w1 = *(const int4*)(fB1 + (k0 >> 1));
    u32x4 q0, q1;
    q0[0] = dqpair((u32)w0.x, s0, c0); q0[1] = dqpair((u32)w0.y, s0, c0);
    q0[2] = dqpair((u32)w0.z, s0, c0); q0[3] = dqpair((u32)w0.w, s0, c0);
    q1[0] = dqpair((u32)w1.x, s1, c1); q1[1] = dqpair((u32)w1.y, s1, c1);
    q1[2] = dqpair((u32)w1.z, s1, c1); q1[3] = dqpair((u32)w1.w, s1, c1);
    *(u32x4*)fBD0 = q0;
    *(u32x4*)fBD1 = q1;

    __syncthreads();

    #pragma unroll
    for (int kk = 0; kk < 2; ++kk) {
      const int koff = (kk * 64 + fk * 16) ^ fswz;
      bf16x8 af[4], bfr[4];
      #pragma unroll
      for (int fm = 0; fm < 4; ++fm)
        af[fm] = *(const bf16x8*)(aRd + fm * 16 * 128 + koff);
      #pragma unroll
      for (int fn = 0; fn < 4; ++fn)
        bfr[fn] = *(const bf16x8*)(bRd + fn * 16 * 128 + koff);
      #pragma unroll
      for (int fm = 0; fm < 4; ++fm)
        #pragma unroll
        for (int fn = 0; fn < 4; ++fn)
          acc[fm][fn] = __builtin_amdgcn_mfma_f32_16x16x32_bf16(
              af[fm], bfr[fn], acc[fm][fn], 0, 0, 0);
    }
    __syncthreads();
  }

  #pragma unroll
  for (int fm = 0; fm < 4; ++fm) {
    #pragma unroll
    for (int r = 0; r < 4; ++r) {
      const size_t mrow = (size_t)(m0 + wm * 64 + fm * 16 + fk * 4 + r) * Nt;
      #pragma unroll
      for (int fn = 0; fn < 4; ++fn)
        Y[mrow + (size_t)(n0 + wn * 64 + fn * 16 + frow)] = acc[fm][fn][r];
    }
  }
}

}  // namespace

extern "C" void kernel_launch(void* const* d_in, const int* in_sizes, int n_in,
                              void* d_out, int out_size, void* d_ws, size_t ws_size,
                              hipStream_t stream) {
  (void)in_sizes; (void)n_in; (void)out_size;
  const float* X = (const float*)d_in[0];
  const int* W   = (const int*)d_in[1];
  const float* S = (const float*)d_in[2];
  float* Y       = (float*)d_out;

  const size_t xbytes = (size_t)Mt * Kt * 2;   // 64 MiB
  const size_t wbytes = (size_t)Nt * Kt * 2;   // 86 MiB

  if (ws_size >= xbytes + wbytes) {
    u16* Xb = (u16*)d_ws;
    u16* Wb = (u16*)((char*)d_ws + xbytes);
    cvt_x<<<dim3(2048), dim3(256), 0, stream>>>(X, (u32*)Xb);
    cvt_w<<<dim3(2048), dim3(256), 0, stream>>>(W, S, (u32*)Wb);
    gemmbr<<<dim3(GRID), dim3(THREADS), 0, stream>>>(Xb, Wb, Y);
  } else {
    gemm_fused<<<dim3((Mt / BM) * (Nt / 128)), dim3(512), 0, stream>>>(X, W, S, Y);
  }
}

// Round 13
// 793.585 us; speedup vs baseline: 1.5544x; 1.5544x over previous
//
#include <hip/hip_runtime.h>
#include <stdint.h>

// W4A16 dequant-GEMM for MI355X (gfx950) — R11 schedule + 32x32x16 MFMA.
// Dtypes (fp16 ref normalized by harness): X f32[8192][4096], W int32[11008][2048]
// (one byte = 2 int4 per element), S f32[11008][32], Y f32[8192][11008].
//
// Fast path: cvt_x (X->bf16) + cvt_w (dequant W->bf16) into d_ws, then bf16 GEMM:
// 256x256 tile, BK=64, 512 thr = 8 waves (2M x 4N), 128x64 out/wave.
// Compute uses mfma_f32_32x32x16_bf16 (2495 TF pipe vs 2075 for 16x16) —
// acc = 8 blocks of 32x32 (f32x16 acc[4][2]), 32 MFMA/wave/K-tile.
// Staging/swizzle/gates identical to R11 (verified): LDS 128 KiB = {A,B} x 2buf
// x 2half x 16KB, 4 phases/K-tile, stage calendar ph0->A1(t+1), ph1->A0(t+2),
// ph2->B0(t+2), ph3->B1(t+2), GATE(6) before tile-ending barrier (cross-wave
// safe: gate->barrier->read), x2 unroll for literal buffer indices.
// Fallback (ws too small): fused single-buffer kernel (round-3-verified algebra).

namespace {

typedef unsigned int u32;
typedef unsigned short u16;
typedef __attribute__((ext_vector_type(8))) short bf16x8;    // 8 bf16 = 4 VGPR
typedef __attribute__((ext_vector_type(4))) float f32x4;
typedef __attribute__((ext_vector_type(16))) float f32x16;   // 32x32 acc block
typedef __attribute__((ext_vector_type(4))) u32 u32x4;

constexpr int Mt = 8192;
constexpr int Nt = 11008;
constexpr int Kt = 4096;
constexpr int KP = Kt / 2;     // int32 per W row
constexpr int NG = 32;         // scale groups
constexpr int BM = 256;
constexpr int BN = 256;
constexpr int BK = 64;
constexpr int THREADS = 512;
constexpr int GRID = (Mt / BM) * (Nt / BN);   // 32*43 = 1376 (div by 8)
constexpr int NKT = Kt / BK;                  // 64 K-tiles
constexpr int NB_CNT = Nt / BN;               // 43

__device__ __forceinline__ u16 f2bf(float f) {   // RNE f32 -> bf16 bits
  u32 u = __float_as_uint(f);
  return (u16)((u + 0x7FFFu + ((u >> 16) & 1u)) >> 16);
}
__device__ __forceinline__ u32 pk2bf(float a, float b) {
  return (u32)f2bf(a) | ((u32)f2bf(b) << 16);
}
__device__ __forceinline__ u32 dqpair(u32 b, float s, float c) {
  float f0 = (float)(b & 15u);
  float f1 = (float)((b >> 4) & 15u);
  return pk2bf(fmaf(f0, s, c), fmaf(f1, s, c));
}
__device__ __forceinline__ void async16(const void* g, void* l) {
  __builtin_amdgcn_global_load_lds(
      (const __attribute__((address_space(1))) u32*)g,
      (__attribute__((address_space(3))) u32*)l, 16, 0, 0);
}

// ---- one-shot converters (HBM-bound, ~60 us total) ----
__global__ __launch_bounds__(256) void cvt_x(const float* __restrict__ X,
                                             u32* __restrict__ O) {
  const int total = Mt * Kt / 4;
  for (int j = blockIdx.x * 256 + threadIdx.x; j < total;
       j += (int)(gridDim.x * 256)) {
    float4 v = ((const float4*)X)[j];
    ((uint2*)O)[j] = make_uint2(pk2bf(v.x, v.y), pk2bf(v.z, v.w));
  }
}

__global__ __launch_bounds__(256) void cvt_w(const int* __restrict__ W,
                                             const float* __restrict__ S,
                                             u32* __restrict__ O) {
  const int total = Nt * KP / 4;
  for (int j = blockIdx.x * 256 + threadIdx.x; j < total;
       j += (int)(gridDim.x * 256)) {
    int4 v = ((const int4*)W)[j];
    int vv[4] = {v.x, v.y, v.z, v.w};
    const int j0 = j * 4;            // flat int32 index = row*2048 + jj
    const int row = j0 >> 11;
    const int jj = j0 & 2047;
    const float* sr = S + (size_t)row * NG;
    u32x4 o;
    #pragma unroll
    for (int e = 0; e < 4; ++e) {
      float s = sr[(jj + e) >> 6];   // group = (2*jj)/128 = jj/64
      o[e] = dqpair((u32)vv[e], s, -8.f * s);
    }
    ((u32x4*)O)[j] = o;              // u32 idx jj holds k=2jj (lo), 2jj+1 (hi)
  }
}

// ---- main GEMM: 256x256, BK=64, 4-phase schedule, 32x32x16 MFMA ----
__global__ __launch_bounds__(THREADS, 2) void gemm32(
    const u16* __restrict__ Xb, const u16* __restrict__ Wb,
    float* __restrict__ Y) {
  // A: [buf][half g] 2x2x16KB at 0..64K; B: same at 64K..128K.
  __shared__ __align__(16) unsigned char smem[131072];

  const int tid  = (int)threadIdx.x;
  const int lane = tid & 63;
  const int wid  = tid >> 6;   // 0..7
  const int wm   = wid >> 2;   // 0..1  (M dir, 128 rows/wave)
  const int wn   = wid & 3;    // 0..3  (N dir, 64 cols/wave)

  // XCD-bijective swizzle (1376 = 8*172); nb fast-varying.
  const int bid = (int)blockIdx.x;
  const int wg  = (bid & 7) * (GRID / 8) + (bid >> 3);
  const int mb  = wg / NB_CNT;
  const int nb  = wg - mb * NB_CNT;
  const int m0  = mb * BM;
  const int n0  = nb * BN;

  // ---- staging (identical to R11): half-tile = 16KB = 128 rows x 128B.
  // rows of 128B = 8 x 16B slots; physical slot = logical ^ (row&7); source
  // pre-swizzled so LDS dest is linear (dest = half_base + issue*8192 + tid*16).
  const int srow = tid >> 3;                       // 0..63
  const int sswz = (tid & 7) ^ (srow & 7);         // logical source slot
  const u16* aRow = Xb + (size_t)(m0 + srow) * Kt + sswz * 8;
  const u16* bRow = Wb + (size_t)(n0 + (srow >> 5) * 64 + (srow & 31)) * Kt + sswz * 8;
  const int ldst = tid * 16;

  // ---- 32x32x16 fragment-read constants ----
  // A-op: row = lane&31, k = (lane>>5)*8 + e (contiguous 8). For k-step ks
  // (0..3): logical 16B slot = ks*2 + (lane>>5); physical = ^ (row&7) = ^(lane&7).
  const int l31  = lane & 31;
  const int khalf = lane >> 5;                // 0..1
  const int l7   = lane & 7;
  // A base (per fg half): fg*16384 + wm*8192 + (q*32 + l31)*128
  const int aRdC = wm * 8192 + l31 * 128;
  // B base (per fnp half): (wn*32 + l31)*128
  const int bRdC = (wn * 32 + l31) * 128;
  int sOff[4];
  #pragma unroll
  for (int ks = 0; ks < 4; ++ks) sOff[ks] = ((ks * 2 + khalf) ^ l7) << 4;

  f32x16 acc[4][2];   // [mb 0..3][nb 0..1], 128 regs
  #pragma unroll
  for (int i = 0; i < 4; ++i)
    #pragma unroll
    for (int j = 0; j < 2; ++j)
      acc[i][j] = (f32x16)(0.f);

  #define GATE(n) asm volatile("s_waitcnt vmcnt(" #n ")" ::: "memory")
  #define BARR()  asm volatile("s_barrier" ::: "memory")

  // Stage half-tile (2 global_load_lds per thread). kt = K-tile index.
  #define STAGE_A(g, buf, kt)                                                  \
    do {                                                                       \
      unsigned char* d_ = smem + (buf) * 32768 + (g) * 16384 + ldst;           \
      const u16* s_ = aRow + (size_t)((g) * 64) * Kt + (kt) * 64;              \
      async16(s_, d_);                                                         \
      async16(s_ + (size_t)128 * Kt, d_ + 8192);                               \
    } while (0)
  #define STAGE_B(p, buf, kt)                                                  \
    do {                                                                       \
      unsigned char* d_ = smem + 65536 + (buf) * 32768 + (p) * 16384 + ldst;   \
      const u16* s_ = bRow + (size_t)((p) * 32) * Kt + (kt) * 64;              \
      async16(s_, d_);                                                         \
      async16(s_ + (size_t)128 * Kt, d_ + 8192);                               \
    } while (0)

  // A fragments for M-half FG (2 sub-blocks q x 4 k-steps = 8 x ds_read_b128).
  #define LD_A(FG, BUF)                                                        \
    do {                                                                       \
      const unsigned char* b_ = smem + (BUF) * 32768 + (FG) * 16384 + aRdC;    \
      _Pragma("unroll")                                                        \
      for (int q_ = 0; q_ < 2; ++q_)                                           \
        _Pragma("unroll")                                                      \
        for (int ks_ = 0; ks_ < 4; ++ks_)                                      \
          af[q_][ks_] = *(const bf16x8*)(b_ + q_ * 4096 + sOff[ks_]);          \
    } while (0)
  // B fragments for N-quadrant P (4 k-steps = 4 x ds_read_b128).
  #define LD_B(DST, P, BUF)                                                    \
    do {                                                                       \
      const unsigned char* b_ =                                                \
          smem + 65536 + (BUF) * 32768 + (P) * 16384 + bRdC;                   \
      _Pragma("unroll")                                                        \
      for (int ks_ = 0; ks_ < 4; ++ks_)                                        \
        DST[ks_] = *(const bf16x8*)(b_ + sOff[ks_]);                           \
    } while (0)

  // Quadrant (FG, FNP): 2 sub-blocks x 4 k-steps = 8 MFMA (32x32x16).
  #define MM_G(FG, FNP, BS, GN)                                                \
    do {                                                                       \
      BARR();                                                                  \
      __builtin_amdgcn_s_setprio(1);                                           \
      _Pragma("unroll")                                                        \
      for (int q_ = 0; q_ < 2; ++q_)                                           \
        _Pragma("unroll")                                                      \
        for (int ks_ = 0; ks_ < 4; ++ks_)                                      \
          acc[(FG) * 2 + q_][FNP] = __builtin_amdgcn_mfma_f32_32x32x16_bf16(   \
              af[q_][ks_], BS[ks_], acc[(FG) * 2 + q_][FNP], 0, 0, 0);         \
      __builtin_amdgcn_s_setprio(0);                                           \
      if ((GN) == 6) { asm volatile("s_waitcnt vmcnt(6)" ::: "memory"); }      \
      else if ((GN) == 0) { asm volatile("s_waitcnt vmcnt(0)" ::: "memory"); } \
      BARR();                                                                  \
    } while (0)

  // One K-tile (4 phases), BUF literal. Stage calendar identical to R11.
  #define TILE(BUF, T, GN_LAST)                                                \
    do {                                                                       \
      LD_A(0, BUF);                                                            \
      LD_B(b0, 0, BUF);                                                        \
      STAGE_A(1, BUF ^ 1, (T) + 1);                                            \
      MM_G(0, 0, b0, -1);                                                      \
      LD_B(b1, 1, BUF);                                                        \
      STAGE_A(0, BUF, (T) + 2);                                                \
      MM_G(0, 1, b1, -1);                                                      \
      LD_A(1, BUF);                                                            \
      STAGE_B(0, BUF, (T) + 2);                                                \
      MM_G(1, 0, b0, -1);                                                      \
      STAGE_B(1, BUF, (T) + 2);                                                \
      MM_G(1, 1, b1, GN_LAST);                                                 \
    } while (0)

  bf16x8 af[2][4];
  bf16x8 b0[4], b1[4];

  // Prologue: 7 half-tiles (14 loads): tile0 full set + tile1 minus A1.
  STAGE_A(0, 0, 0);   // A0(0)
  STAGE_B(0, 0, 0);   // B0(0)
  STAGE_B(1, 0, 0);   // B1(0)
  STAGE_A(1, 0, 0);   // A1(0)
  STAGE_A(0, 1, 1);   // A0(1)
  STAGE_B(0, 1, 1);   // B0(1)
  STAGE_B(1, 1, 1);   // B1(1)
  GATE(6);            // tile 0 fully landed (newest 6 = A0/B0/B1 of tile 1)
  BARR();             // ...visible to ALL waves' ds_reads

  // Steady loop: tiles 0..61 as 31 x (2 K-tiles), literal buffer indices.
  #pragma unroll 1
  for (int t0 = 0; t0 < NKT - 2; t0 += 2) {
    TILE(0, t0, 6);
    TILE(1, t0 + 1, 6);
  }

  // Peeled t = 62 (buf 0): only A1(63) stage remains; drain at tile end.
  {
    LD_A(0, 0);
    LD_B(b0, 0, 0);
    STAGE_A(1, 1, 63);
    MM_G(0, 0, b0, -1);
    LD_B(b1, 1, 0);
    MM_G(0, 1, b1, -1);
    LD_A(1, 0);
    MM_G(1, 0, b0, -1);
    MM_G(1, 1, b1, 0);   // GATE(0): tile 63 fully landed before barrier
  }
  // Peeled t = 63 (buf 1): no stages, no gates.
  {
    LD_A(0, 1);
    LD_B(b0, 0, 1);
    MM_G(0, 0, b0, -1);
    LD_B(b1, 1, 1);
    MM_G(0, 1, b1, -1);
    LD_A(1, 1);
    MM_G(1, 0, b0, -1);
    MM_G(1, 1, b1, -1);
  }

  #undef GATE
  #undef BARR
  #undef STAGE_A
  #undef STAGE_B
  #undef LD_A
  #undef LD_B
  #undef MM_G
  #undef TILE

  // Epilogue: 32x32 C/D mapping (m74/m101): col = lane&31,
  // row = (reg&3) + 8*(reg>>2) + 4*(lane>>5).
  #pragma unroll
  for (int mq = 0; mq < 4; ++mq) {
    #pragma unroll
    for (int nq = 0; nq < 2; ++nq) {
      #pragma unroll
      for (int r = 0; r < 16; ++r) {
        const int row = (r & 3) + 8 * (r >> 2) + 4 * khalf;
        Y[(size_t)(m0 + wm * 128 + mq * 32 + row) * Nt +
          (size_t)(n0 + wn * 64 + nq * 32 + l31)] = acc[mq][nq][r];
      }
    }
  }
}

// ---- fallback: fused single-buffer kernel (round-3 verified algebra) ----
__global__ __launch_bounds__(512) void gemm_fused(
    const float* __restrict__ Xf, const int* __restrict__ W,
    const float* __restrict__ S, float* __restrict__ Y) {
  constexpr int FBN = 128;
  constexpr int FNB = Nt / FBN;   // 86
  constexpr int FBK = 64;
  constexpr int FNKT = Kt / FBK;
  __shared__ __align__(16) unsigned char Alds[BM * FBK * 2];
  __shared__ __align__(16) unsigned char Blds[FBN * FBK * 2];

  const int tid = (int)threadIdx.x;
  const int lane = tid & 63;
  const int wid = tid >> 6;
  const int wm = wid >> 1;
  const int wn = wid & 1;

  const int bid = (int)blockIdx.x;
  const int fgrid = (Mt / BM) * FNB;
  const int wg = (bid & 7) * (fgrid / 8) + (bid >> 3);
  const int mb = wg / FNB;
  const int nb = wg - mb * FNB;
  const int m0 = mb * BM;
  const int n0 = nb * FBN;

  const int frow = lane & 15;
  const int fk = lane >> 4;
  const int fswz = (lane & 7) << 4;
  const unsigned char* aRd = Alds + (wm * 64 + frow) * 128;
  const unsigned char* bRd = Blds + (wn * 64 + frow) * 128;

  f32x4 acc[4][4];
  #pragma unroll
  for (int i = 0; i < 4; ++i)
    #pragma unroll
    for (int j = 0; j < 4; ++j) acc[i][j] = f32x4{0.f, 0.f, 0.f, 0.f};

  const int arow = tid >> 3, acol = tid & 7;
  const float* fA = Xf + (size_t)(m0 + arow) * Kt + acol * 8;
  unsigned char* fAD = Alds + arow * 128 + ((acol ^ (arow & 7)) << 4);
  const int nloc = tid >> 3, c4 = tid & 7;
  const int* fB0 = W + (size_t)(n0 + nloc) * KP + c4 * 4;
  const int* fB1 = fB0 + (size_t)64 * KP;
  const float* sp0 = S + (size_t)(n0 + nloc) * NG;
  const float* sp1 = sp0 + (size_t)64 * NG;
  unsigned char* fBD0 = Blds + nloc * 128 + ((c4 ^ (nloc & 7)) << 4);
  unsigned char* fBD1 = fBD0 + 64 * 128;

  #pragma unroll 1
  for (int kt = 0; kt < FNKT; ++kt) {
    const int k0 = kt * FBK;
    #pragma unroll
    for (int p = 0; p < 4; ++p) {
      float4 x0 = *(const float4*)(fA + (size_t)p * 64 * Kt + k0);
      float4 x1 = *(const float4*)(fA + (size_t)p * 64 * Kt + k0 + 4);
      u32x4 q;
      q[0] = pk2bf(x0.x, x0.y); q[1] = pk2bf(x0.z, x0.w);
      q[2] = pk2bf(x1.x, x1.y); q[3] = pk2bf(x1.z, x1.w);
      *(u32x4*)(fAD + p * 64 * 128) = q;
    }
    const int g = k0 >> 7;
    const float s0 = sp0[g], s1 = sp1[g];
    const float c0 = -8.f * s0, c1 = -8.f * s1;
    const int4 w0 = *(const int4*)(fB0 + (k0 >> 1));
    const int4 w1 = *(const int4*)(fB1 + (k0 >> 1));
    u32x4 q0, q1;
    q0[0] = dqpair((u32)w0.x, s0, c0); q0[1] = dqpair((u32)w0.y, s0, c0);
    q0[2] = dqpair((u32)w0.z, s0, c0); q0[3] = dqpair((u32)w0.w, s0, c0);
    q1[0] = dqpair((u32)w1.x, s1, c1); q1[1] = dqpair((u32)w1.y, s1, c1);
    q1[2] = dqpair((u32)w1.z, s1, c1); q1[3] = dqpair((u32)w1.w, s1, c1);
    *(u32x4*)fBD0 = q0;
    *(u32x4*)fBD1 = q1;

    __syncthreads();

    #pragma unroll
    for (int kk = 0; kk < 2; ++kk) {
      const int koff = (kk * 64 + fk * 16) ^ fswz;
      bf16x8 af[4], bfr[4];
      #pragma unroll
      for (int fm = 0; fm < 4; ++fm)
        af[fm] = *(const bf16x8*)(aRd + fm * 16 * 128 + koff);
      #pragma unroll
      for (int fn = 0; fn < 4; ++fn)
        bfr[fn] = *(const bf16x8*)(bRd + fn * 16 * 128 + koff);
      #pragma unroll
      for (int fm = 0; fm < 4; ++fm)
        #pragma unroll
        for (int fn = 0; fn < 4; ++fn)
          acc[fm][fn] = __builtin_amdgcn_mfma_f32_16x16x32_bf16(
              af[fm], bfr[fn], acc[fm][fn], 0, 0, 0);
    }
    __syncthreads();
  }

  #pragma unroll
  for (int fm = 0; fm < 4; ++fm) {
    #pragma unroll
    for (int r = 0; r < 4; ++r) {
      const size_t mrow = (size_t)(m0 + wm * 64 + fm * 16 + fk * 4 + r) * Nt;
      #pragma unroll
      for (int fn = 0; fn < 4; ++fn)
        Y[mrow + (size_t)(n0 + wn * 64 + fn * 16 + frow)] = acc[fm][fn][r];
    }
  }
}

}  // namespace

extern "C" void kernel_launch(void* const* d_in, const int* in_sizes, int n_in,
                              void* d_out, int out_size, void* d_ws, size_t ws_size,
                              hipStream_t stream) {
  (void)in_sizes; (void)n_in; (void)out_size;
  const float* X = (const float*)d_in[0];
  const int* W   = (const int*)d_in[1];
  const float* S = (const float*)d_in[2];
  float* Y       = (float*)d_out;

  const size_t xbytes = (size_t)Mt * Kt * 2;   // 64 MiB
  const size_t wbytes = (size_t)Nt * Kt * 2;   // 86 MiB

  if (ws_size >= xbytes + wbytes) {
    u16* Xb = (u16*)d_ws;
    u16* Wb = (u16*)((char*)d_ws + xbytes);
    cvt_x<<<dim3(2048), dim3(256), 0, stream>>>(X, (u32*)Xb);
    cvt_w<<<dim3(2048), dim3(256), 0, stream>>>(W, S, (u32*)Wb);
    gemm32<<<dim3(GRID), dim3(THREADS), 0, stream>>>(Xb, Wb, Y);
  } else {
    gemm_fused<<<dim3((Mt / BM) * (Nt / 128)), dim3(512), 0, stream>>>(X, W, S, Y);
  }
}

// Round 14
// 791.799 us; speedup vs baseline: 1.5579x; 1.0023x over previous
//
#include <hip/hip_runtime.h>
#include <stdint.h>

// W4A16 dequant-GEMM for MI355X (gfx950) — 32x32x16 MFMA, conflict-free swizzle.
// Dtypes (fp16 ref normalized by harness): X f32[8192][4096], W int32[11008][2048]
// (one byte = 2 int4 per element), S f32[11008][32], Y f32[8192][11008].
//
// Fast path: cvt_x (X->bf16) + cvt_w (dequant W->bf16) into d_ws, then bf16 GEMM:
// 256x256 tile, BK=64, 512 thr = 8 waves (2M x 4N), 128x64 out/wave,
// mfma_f32_32x32x16_bf16 (acc f32x16[4][2]). Schedule = R11 (verified): LDS
// 128 KiB = {A,B} x 2buf x 2half x 16KB, 4 phases/K-tile, stage calendar
// ph0->A1(t+1), ph1->A0(t+2), ph2->B0(t+2), ph3->B1(t+2), GATE(6) before the
// tile-ending barrier (gate->barrier->read), x2 unroll for literal buf indices.
// SWIZZLE FIX (R13 post-mortem): 32x32 reads have khalf=lane>>5 (1 bit) in the
// slot, so slot = (2ks+khalf)^(row&7) gives the 8 lanes sharing lane&7 only 2
// distinct slots -> 4-way bank aliasing (6.76e7 counter = 4 cyc/read). New
// involution f(row) = (row&7) ^ (((row>>3)&3)<<1): those lanes now span 8
// distinct slots; every 8-lane clock group still covers all 32 banks.
// Fallback (ws too small): fused single-buffer kernel (round-3-verified algebra).

namespace {

typedef unsigned int u32;
typedef unsigned short u16;
typedef __attribute__((ext_vector_type(8))) short bf16x8;    // 8 bf16 = 4 VGPR
typedef __attribute__((ext_vector_type(4))) float f32x4;
typedef __attribute__((ext_vector_type(16))) float f32x16;   // 32x32 acc block
typedef __attribute__((ext_vector_type(4))) u32 u32x4;

constexpr int Mt = 8192;
constexpr int Nt = 11008;
constexpr int Kt = 4096;
constexpr int KP = Kt / 2;     // int32 per W row
constexpr int NG = 32;         // scale groups
constexpr int BM = 256;
constexpr int BN = 256;
constexpr int BK = 64;
constexpr int THREADS = 512;
constexpr int GRID = (Mt / BM) * (Nt / BN);   // 32*43 = 1376 (div by 8)
constexpr int NKT = Kt / BK;                  // 64 K-tiles
constexpr int NB_CNT = Nt / BN;               // 43

__device__ __forceinline__ u16 f2bf(float f) {   // RNE f32 -> bf16 bits
  u32 u = __float_as_uint(f);
  return (u16)((u + 0x7FFFu + ((u >> 16) & 1u)) >> 16);
}
__device__ __forceinline__ u32 pk2bf(float a, float b) {
  return (u32)f2bf(a) | ((u32)f2bf(b) << 16);
}
__device__ __forceinline__ u32 dqpair(u32 b, float s, float c) {
  float f0 = (float)(b & 15u);
  float f1 = (float)((b >> 4) & 15u);
  return pk2bf(fmaf(f0, s, c), fmaf(f1, s, c));
}
__device__ __forceinline__ void async16(const void* g, void* l) {
  __builtin_amdgcn_global_load_lds(
      (const __attribute__((address_space(1))) u32*)g,
      (__attribute__((address_space(3))) u32*)l, 16, 0, 0);
}

// ---- one-shot converters (HBM-bound, ~60 us total) ----
__global__ __launch_bounds__(256) void cvt_x(const float* __restrict__ X,
                                             u32* __restrict__ O) {
  const int total = Mt * Kt / 4;
  for (int j = blockIdx.x * 256 + threadIdx.x; j < total;
       j += (int)(gridDim.x * 256)) {
    float4 v = ((const float4*)X)[j];
    ((uint2*)O)[j] = make_uint2(pk2bf(v.x, v.y), pk2bf(v.z, v.w));
  }
}

__global__ __launch_bounds__(256) void cvt_w(const int* __restrict__ W,
                                             const float* __restrict__ S,
                                             u32* __restrict__ O) {
  const int total = Nt * KP / 4;
  for (int j = blockIdx.x * 256 + threadIdx.x; j < total;
       j += (int)(gridDim.x * 256)) {
    int4 v = ((const int4*)W)[j];
    int vv[4] = {v.x, v.y, v.z, v.w};
    const int j0 = j * 4;            // flat int32 index = row*2048 + jj
    const int row = j0 >> 11;
    const int jj = j0 & 2047;
    const float* sr = S + (size_t)row * NG;
    u32x4 o;
    #pragma unroll
    for (int e = 0; e < 4; ++e) {
      float s = sr[(jj + e) >> 6];   // group = (2*jj)/128 = jj/64
      o[e] = dqpair((u32)vv[e], s, -8.f * s);
    }
    ((u32x4*)O)[j] = o;              // u32 idx jj holds k=2jj (lo), 2jj+1 (hi)
  }
}

// ---- main GEMM: 256x256, BK=64, 4-phase schedule, 32x32x16 MFMA ----
__global__ __launch_bounds__(THREADS, 2) void gemm32(
    const u16* __restrict__ Xb, const u16* __restrict__ Wb,
    float* __restrict__ Y) {
  // A: [buf][half g] 2x2x16KB at 0..64K; B: same at 64K..128K.
  __shared__ __align__(16) unsigned char smem[131072];

  const int tid  = (int)threadIdx.x;
  const int lane = tid & 63;
  const int wid  = tid >> 6;   // 0..7
  const int wm   = wid >> 2;   // 0..1  (M dir, 128 rows/wave)
  const int wn   = wid & 3;    // 0..3  (N dir, 64 cols/wave)

  // XCD-bijective swizzle (1376 = 8*172); nb fast-varying.
  const int bid = (int)blockIdx.x;
  const int wg  = (bid & 7) * (GRID / 8) + (bid >> 3);
  const int mb  = wg / NB_CNT;
  const int nb  = wg - mb * NB_CNT;
  const int m0  = mb * BM;
  const int n0  = nb * BN;

  // ---- staging: half-tile = 16KB = 128 rows x 128B; per thread 2x16B.
  // Involution on 16B slots: f(row) = (row&7) ^ (((row>>3)&3)<<1).
  // DMA writes linear (phys slot = tid&7 at row tid>>3 [+64/issue]); source
  // reads logical slot = phys ^ f(row). (row>>3)&3 is issue-invariant (64|row).
  const int srow = tid >> 3;                       // 0..63
  const int sswz = (tid & 7) ^ ((tid >> 3) & 7) ^ (((tid >> 6) & 3) << 1);
  const u16* aRow = Xb + (size_t)(m0 + srow) * Kt + sswz * 8;
  const u16* bRow = Wb + (size_t)(n0 + (srow >> 5) * 64 + (srow & 31)) * Kt + sswz * 8;
  const int ldst = tid * 16;

  // ---- 32x32x16 fragment-read constants ----
  // A-op: row = lane&31 (+q*32), k = (lane>>5)*8 + e. k-step ks: logical slot
  // = ks*2 + khalf; physical = logical ^ f(row), f row-bits invariant to +32.
  const int l31  = lane & 31;
  const int khalf = lane >> 5;                // 0..1
  const int l7   = lane & 7;
  const int fr   = l7 ^ (((l31 >> 3) & 3) << 1);   // f(row) for this lane
  const int aRdC = wm * 8192 + l31 * 128;     // + fg*16384 + q*4096
  const int bRdC = (wn * 32 + l31) * 128;
  int sOff[4];
  #pragma unroll
  for (int ks = 0; ks < 4; ++ks) sOff[ks] = ((ks * 2 + khalf) ^ fr) << 4;

  f32x16 acc[4][2];   // [mq 0..3][nq 0..1], 128 regs
  #pragma unroll
  for (int i = 0; i < 4; ++i)
    #pragma unroll
    for (int j = 0; j < 2; ++j)
      acc[i][j] = (f32x16)(0.f);

  #define GATE(n) asm volatile("s_waitcnt vmcnt(" #n ")" ::: "memory")
  #define BARR()  asm volatile("s_barrier" ::: "memory")

  // Stage half-tile (2 global_load_lds per thread). kt = K-tile index.
  #define STAGE_A(g, buf, kt)                                                  \
    do {                                                                       \
      unsigned char* d_ = smem + (buf) * 32768 + (g) * 16384 + ldst;           \
      const u16* s_ = aRow + (size_t)((g) * 64) * Kt + (kt) * 64;              \
      async16(s_, d_);                                                         \
      async16(s_ + (size_t)128 * Kt, d_ + 8192);                               \
    } while (0)
  #define STAGE_B(p, buf, kt)                                                  \
    do {                                                                       \
      unsigned char* d_ = smem + 65536 + (buf) * 32768 + (p) * 16384 + ldst;   \
      const u16* s_ = bRow + (size_t)((p) * 32) * Kt + (kt) * 64;              \
      async16(s_, d_);                                                         \
      async16(s_ + (size_t)128 * Kt, d_ + 8192);                               \
    } while (0)

  // A fragments for M-half FG (2 sub-blocks q x 4 k-steps = 8 x ds_read_b128).
  #define LD_A(FG, BUF)                                                        \
    do {                                                                       \
      const unsigned char* b_ = smem + (BUF) * 32768 + (FG) * 16384 + aRdC;    \
      _Pragma("unroll")                                                        \
      for (int q_ = 0; q_ < 2; ++q_)                                           \
        _Pragma("unroll")                                                      \
        for (int ks_ = 0; ks_ < 4; ++ks_)                                      \
          af[q_][ks_] = *(const bf16x8*)(b_ + q_ * 4096 + sOff[ks_]);          \
    } while (0)
  // B fragments for N-quadrant P (4 k-steps = 4 x ds_read_b128).
  #define LD_B(DST, P, BUF)                                                    \
    do {                                                                       \
      const unsigned char* b_ =                                                \
          smem + 65536 + (BUF) * 32768 + (P) * 16384 + bRdC;                   \
      _Pragma("unroll")                                                        \
      for (int ks_ = 0; ks_ < 4; ++ks_)                                        \
        DST[ks_] = *(const bf16x8*)(b_ + sOff[ks_]);                           \
    } while (0)

  // Quadrant (FG, FNP): 2 sub-blocks x 4 k-steps = 8 MFMA (32x32x16).
  #define MM_G(FG, FNP, BS, GN)                                                \
    do {                                                                       \
      BARR();                                                                  \
      __builtin_amdgcn_s_setprio(1);                                           \
      _Pragma("unroll")                                                        \
      for (int q_ = 0; q_ < 2; ++q_)                                           \
        _Pragma("unroll")                                                      \
        for (int ks_ = 0; ks_ < 4; ++ks_)                                      \
          acc[(FG) * 2 + q_][FNP] = __builtin_amdgcn_mfma_f32_32x32x16_bf16(   \
              af[q_][ks_], BS[ks_], acc[(FG) * 2 + q_][FNP], 0, 0, 0);         \
      __builtin_amdgcn_s_setprio(0);                                           \
      if ((GN) == 6) { asm volatile("s_waitcnt vmcnt(6)" ::: "memory"); }      \
      else if ((GN) == 0) { asm volatile("s_waitcnt vmcnt(0)" ::: "memory"); } \
      BARR();                                                                  \
    } while (0)

  // One K-tile (4 phases), BUF literal. Stage calendar identical to R11.
  #define TILE(BUF, T, GN_LAST)                                                \
    do {                                                                       \
      LD_A(0, BUF);                                                            \
      LD_B(b0, 0, BUF);                                                        \
      STAGE_A(1, BUF ^ 1, (T) + 1);                                            \
      MM_G(0, 0, b0, -1);                                                      \
      LD_B(b1, 1, BUF);                                                        \
      STAGE_A(0, BUF, (T) + 2);                                                \
      MM_G(0, 1, b1, -1);                                                      \
      LD_A(1, BUF);                                                            \
      STAGE_B(0, BUF, (T) + 2);                                                \
      MM_G(1, 0, b0, -1);                                                      \
      STAGE_B(1, BUF, (T) + 2);                                                \
      MM_G(1, 1, b1, GN_LAST);                                                 \
    } while (0)

  bf16x8 af[2][4];
  bf16x8 b0[4], b1[4];

  // Prologue: 7 half-tiles (14 loads): tile0 full set + tile1 minus A1.
  STAGE_A(0, 0, 0);   // A0(0)
  STAGE_B(0, 0, 0);   // B0(0)
  STAGE_B(1, 0, 0);   // B1(0)
  STAGE_A(1, 0, 0);   // A1(0)
  STAGE_A(0, 1, 1);   // A0(1)
  STAGE_B(0, 1, 1);   // B0(1)
  STAGE_B(1, 1, 1);   // B1(1)
  GATE(6);            // tile 0 fully landed (newest 6 = A0/B0/B1 of tile 1)
  BARR();             // ...visible to ALL waves' ds_reads

  // Steady loop: tiles 0..61 as 31 x (2 K-tiles), literal buffer indices.
  #pragma unroll 1
  for (int t0 = 0; t0 < NKT - 2; t0 += 2) {
    TILE(0, t0, 6);
    TILE(1, t0 + 1, 6);
  }

  // Peeled t = 62 (buf 0): only A1(63) stage remains; drain at tile end.
  {
    LD_A(0, 0);
    LD_B(b0, 0, 0);
    STAGE_A(1, 1, 63);
    MM_G(0, 0, b0, -1);
    LD_B(b1, 1, 0);
    MM_G(0, 1, b1, -1);
    LD_A(1, 0);
    MM_G(1, 0, b0, -1);
    MM_G(1, 1, b1, 0);   // GATE(0): tile 63 fully landed before barrier
  }
  // Peeled t = 63 (buf 1): no stages, no gates.
  {
    LD_A(0, 1);
    LD_B(b0, 0, 1);
    MM_G(0, 0, b0, -1);
    LD_B(b1, 1, 1);
    MM_G(0, 1, b1, -1);
    LD_A(1, 1);
    MM_G(1, 0, b0, -1);
    MM_G(1, 1, b1, -1);
  }

  #undef GATE
  #undef BARR
  #undef STAGE_A
  #undef STAGE_B
  #undef LD_A
  #undef LD_B
  #undef MM_G
  #undef TILE

  // Epilogue: 32x32 C/D mapping (m74/m101): col = lane&31,
  // row = (reg&3) + 8*(reg>>2) + 4*(lane>>5).
  #pragma unroll
  for (int mq = 0; mq < 4; ++mq) {
    #pragma unroll
    for (int nq = 0; nq < 2; ++nq) {
      #pragma unroll
      for (int r = 0; r < 16; ++r) {
        const int row = (r & 3) + 8 * (r >> 2) + 4 * khalf;
        Y[(size_t)(m0 + wm * 128 + mq * 32 + row) * Nt +
          (size_t)(n0 + wn * 64 + nq * 32 + l31)] = acc[mq][nq][r];
      }
    }
  }
}

// ---- fallback: fused single-buffer kernel (round-3 verified algebra) ----
__global__ __launch_bounds__(512) void gemm_fused(
    const float* __restrict__ Xf, const int* __restrict__ W,
    const float* __restrict__ S, float* __restrict__ Y) {
  constexpr int FBN = 128;
  constexpr int FNB = Nt / FBN;   // 86
  constexpr int FBK = 64;
  constexpr int FNKT = Kt / FBK;
  __shared__ __align__(16) unsigned char Alds[BM * FBK * 2];
  __shared__ __align__(16) unsigned char Blds[FBN * FBK * 2];

  const int tid = (int)threadIdx.x;
  const int lane = tid & 63;
  const int wid = tid >> 6;
  const int wm = wid >> 1;
  const int wn = wid & 1;

  const int bid = (int)blockIdx.x;
  const int fgrid = (Mt / BM) * FNB;
  const int wg = (bid & 7) * (fgrid / 8) + (bid >> 3);
  const int mb = wg / FNB;
  const int nb = wg - mb * FNB;
  const int m0 = mb * BM;
  const int n0 = nb * FBN;

  const int frow = lane & 15;
  const int fk = lane >> 4;
  const int fswz = (lane & 7) << 4;
  const unsigned char* aRd = Alds + (wm * 64 + frow) * 128;
  const unsigned char* bRd = Blds + (wn * 64 + frow) * 128;

  f32x4 acc[4][4];
  #pragma unroll
  for (int i = 0; i < 4; ++i)
    #pragma unroll
    for (int j = 0; j < 4; ++j) acc[i][j] = f32x4{0.f, 0.f, 0.f, 0.f};

  const int arow = tid >> 3, acol = tid & 7;
  const float* fA = Xf + (size_t)(m0 + arow) * Kt + acol * 8;
  unsigned char* fAD = Alds + arow * 128 + ((acol ^ (arow & 7)) << 4);
  const int nloc = tid >> 3, c4 = tid & 7;
  const int* fB0 = W + (size_t)(n0 + nloc) * KP + c4 * 4;
  const int* fB1 = fB0 + (size_t)64 * KP;
  const float* sp0 = S + (size_t)(n0 + nloc) * NG;
  const float* sp1 = sp0 + (size_t)64 * NG;
  unsigned char* fBD0 = Blds + nloc * 128 + ((c4 ^ (nloc & 7)) << 4);
  unsigned char* fBD1 = fBD0 + 64 * 128;

  #pragma unroll 1
  for (int kt = 0; kt < FNKT; ++kt) {
    const int k0 = kt * FBK;
    #pragma unroll
    for (int p = 0; p < 4; ++p) {
      float4 x0 = *(const float4*)(fA + (size_t)p * 64 * Kt + k0);
      float4 x1 = *(const float4*)(fA + (size_t)p * 64 * Kt + k0 + 4);
      u32x4 q;
      q[0] = pk2bf(x0.x, x0.y); q[1] = pk2bf(x0.z, x0.w);
      q[2] = pk2bf(x1.x, x1.y); q[3] = pk2bf(x1.z, x1.w);
      *(u32x4*)(fAD + p * 64 * 128) = q;
    }
    const int g = k0 >> 7;
    const float s0 = sp0[g], s1 = sp1[g];
    const float c0 = -8.f * s0, c1 = -8.f * s1;
    const int4 w0 = *(const int4*)(fB0 + (k0 >> 1));
    const int4 w1 = *(const int4*)(fB1 + (k0 >> 1));
    u32x4 q0, q1;
    q0[0] = dqpair((u32)w0.x, s0, c0); q0[1] = dqpair((u32)w0.y, s0, c0);
    q0[2] = dqpair((u32)w0.z, s0, c0); q0[3] = dqpair((u32)w0.w, s0, c0);
    q1[0] = dqpair((u32)w1.x, s1, c1); q1[1] = dqpair((u32)w1.y, s1, c1);
    q1[2] = dqpair((u32)w1.z, s1, c1); q1[3] = dqpair((u32)w1.w, s1, c1);
    *(u32x4*)fBD0 = q0;
    *(u32x4*)fBD1 = q1;

    __syncthreads();

    #pragma unroll
    for (int kk = 0; kk < 2; ++kk) {
      const int koff = (kk * 64 + fk * 16) ^ fswz;
      bf16x8 af[4], bfr[4];
      #pragma unroll
      for (int fm = 0; fm < 4; ++fm)
        af[fm] = *(const bf16x8*)(aRd + fm * 16 * 128 + koff);
      #pragma unroll
      for (int fn = 0; fn < 4; ++fn)
        bfr[fn] = *(const bf16x8*)(bRd + fn * 16 * 128 + koff);
      #pragma unroll
      for (int fm = 0; fm < 4; ++fm)
        #pragma unroll
        for (int fn = 0; fn < 4; ++fn)
          acc[fm][fn] = __builtin_amdgcn_mfma_f32_16x16x32_bf16(
              af[fm], bfr[fn], acc[fm][fn], 0, 0, 0);
    }
    __syncthreads();
  }

  #pragma unroll
  for (int fm = 0; fm < 4; ++fm) {
    #pragma unroll
    for (int r = 0; r < 4; ++r) {
      const size_t mrow = (size_t)(m0 + wm * 64 + fm * 16 + fk * 4 + r) * Nt;
      #pragma unroll
      for (int fn = 0; fn < 4; ++fn)
        Y[mrow + (size_t)(n0 + wn * 64 + fn * 16 + frow)] = acc[fm][fn][r];
    }
  }
}

}  // namespace

extern "C" void kernel_launch(void* const* d_in, const int* in_sizes, int n_in,
                              void* d_out, int out_size, void* d_ws, size_t ws_size,
                              hipStream_t stream) {
  (void)in_sizes; (void)n_in; (void)out_size;
  const float* X = (const float*)d_in[0];
  const int* W   = (const int*)d_in[1];
  const float* S = (const float*)d_in[2];
  float* Y       = (float*)d_out;

  const size_t xbytes = (size_t)Mt * Kt * 2;   // 64 MiB
  const size_t wbytes = (size_t)Nt * Kt * 2;   // 86 MiB

  if (ws_size >= xbytes + wbytes) {
    u16* Xb = (u16*)d_ws;
    u16* Wb = (u16*)((char*)d_ws + xbytes);
    cvt_x<<<dim3(2048), dim3(256), 0, stream>>>(X, (u32*)Xb);
    cvt_w<<<dim3(2048), dim3(256), 0, stream>>>(W, S, (u32*)Wb);
    gemm32<<<dim3(GRID), dim3(THREADS), 0, stream>>>(Xb, Wb, Y);
  } else {
    gemm_fused<<<dim3((Mt / BM) * (Nt / 128)), dim3(512), 0, stream>>>(X, W, S, Y);
  }
}

// Round 15
// 710.214 us; speedup vs baseline: 1.7368x; 1.1149x over previous
//
#include <hip/hip_runtime.h>
#include <stdint.h>

// W4A16 dequant-GEMM for MI355X (gfx950) — R11 schedule + kk-outer MFMA order.
// Dtypes (fp16 ref normalized by harness): X f32[8192][4096], W int32[11008][2048]
// (one byte = 2 int4 per element), S f32[11008][32], Y f32[8192][11008].
//
// Fast path: cvt_x (X->bf16) + cvt_w (dequant W->bf16) into d_ws, then bf16 GEMM:
// 256x256 tile, BK=64, 512 thr = 8 waves (2M x 4N), 128x64 out/wave (acc[8][4]),
// LDS 128 KiB = {A,B} x 2buf x 2half x 16KB. Per K-tile 4 phases (C-quadrants):
// {ds_read quadrant, stage 1 half-tile} -> barrier -> setprio(1) 16xMFMA -> barrier.
// x2 main-loop unroll for literal LDS buffer indices (R11). GATE(6) once per
// tile BEFORE the tile-ending barrier (gate->barrier->read, R9 race fix).
// NEW (R14 post-mortem): MFMA cluster ordered kk -> fm -> fn, so consecutive
// MFMAs hit different accumulators (dependency distance 8, was 1). R11's
// kk-innermost chained same-acc MFMAs back-to-back at latency (~3-4x throughput),
// pinning MfmaUtil at ~50% with only 4 barrier-synced waves/SIMD to cover it.
// 32x32x16 branch (R13/R14) abandoned: bank-conflict counter identical across
// provably-different swizzles -> model wrong, regressed vs R11.
// Fallback (ws too small): fused single-buffer kernel (round-3-verified algebra).

namespace {

typedef unsigned int u32;
typedef unsigned short u16;
typedef __attribute__((ext_vector_type(8))) short bf16x8;   // 8 bf16 = 4 VGPR
typedef __attribute__((ext_vector_type(4))) float f32x4;
typedef __attribute__((ext_vector_type(4))) u32 u32x4;

constexpr int Mt = 8192;
constexpr int Nt = 11008;
constexpr int Kt = 4096;
constexpr int KP = Kt / 2;     // int32 per W row
constexpr int NG = 32;         // scale groups
constexpr int BM = 256;
constexpr int BN = 256;
constexpr int BK = 64;
constexpr int THREADS = 512;
constexpr int GRID = (Mt / BM) * (Nt / BN);   // 32*43 = 1376 (div by 8)
constexpr int NKT = Kt / BK;                  // 64 K-tiles
constexpr int NB_CNT = Nt / BN;               // 43

__device__ __forceinline__ u16 f2bf(float f) {   // RNE f32 -> bf16 bits
  u32 u = __float_as_uint(f);
  return (u16)((u + 0x7FFFu + ((u >> 16) & 1u)) >> 16);
}
__device__ __forceinline__ u32 pk2bf(float a, float b) {
  return (u32)f2bf(a) | ((u32)f2bf(b) << 16);
}
__device__ __forceinline__ u32 dqpair(u32 b, float s, float c) {
  float f0 = (float)(b & 15u);
  float f1 = (float)((b >> 4) & 15u);
  return pk2bf(fmaf(f0, s, c), fmaf(f1, s, c));
}
__device__ __forceinline__ void async16(const void* g, void* l) {
  __builtin_amdgcn_global_load_lds(
      (const __attribute__((address_space(1))) u32*)g,
      (__attribute__((address_space(3))) u32*)l, 16, 0, 0);
}

// ---- one-shot converters (HBM-bound, ~60 us total) ----
__global__ __launch_bounds__(256) void cvt_x(const float* __restrict__ X,
                                             u32* __restrict__ O) {
  const int total = Mt * Kt / 4;
  for (int j = blockIdx.x * 256 + threadIdx.x; j < total;
       j += (int)(gridDim.x * 256)) {
    float4 v = ((const float4*)X)[j];
    ((uint2*)O)[j] = make_uint2(pk2bf(v.x, v.y), pk2bf(v.z, v.w));
  }
}

__global__ __launch_bounds__(256) void cvt_w(const int* __restrict__ W,
                                             const float* __restrict__ S,
                                             u32* __restrict__ O) {
  const int total = Nt * KP / 4;
  for (int j = blockIdx.x * 256 + threadIdx.x; j < total;
       j += (int)(gridDim.x * 256)) {
    int4 v = ((const int4*)W)[j];
    int vv[4] = {v.x, v.y, v.z, v.w};
    const int j0 = j * 4;            // flat int32 index = row*2048 + jj
    const int row = j0 >> 11;
    const int jj = j0 & 2047;
    const float* sr = S + (size_t)row * NG;
    u32x4 o;
    #pragma unroll
    for (int e = 0; e < 4; ++e) {
      float s = sr[(jj + e) >> 6];   // group = (2*jj)/128 = jj/64
      o[e] = dqpair((u32)vv[e], s, -8.f * s);
    }
    ((u32x4*)O)[j] = o;              // u32 idx jj holds k=2jj (lo), 2jj+1 (hi)
  }
}

// ---- main GEMM: 256x256, BK=64, 4-phase schedule, x2 unroll ----
__global__ __launch_bounds__(THREADS, 2) void gemm8p(
    const u16* __restrict__ Xb, const u16* __restrict__ Wb,
    float* __restrict__ Y) {
  // A: [buf][half g] 2x2x16KB at 0..64K; B: same at 64K..128K.
  __shared__ __align__(16) unsigned char smem[131072];

  const int tid  = (int)threadIdx.x;
  const int lane = tid & 63;
  const int wid  = tid >> 6;   // 0..7
  const int wm   = wid >> 2;   // 0..1  (M dir, 128 rows/wave)
  const int wn   = wid & 3;    // 0..3  (N dir, 64 cols/wave)

  // XCD-bijective swizzle (1376 = 8*172); nb fast-varying.
  const int bid = (int)blockIdx.x;
  const int wg  = (bid & 7) * (GRID / 8) + (bid >> 3);
  const int mb  = wg / NB_CNT;
  const int nb  = wg - mb * NB_CNT;
  const int m0  = mb * BM;
  const int n0  = nb * BN;

  // ---- staging: half-tile = 16KB = 128 rows x 128B; per thread 2x16B.
  // rows of 128B = 8 x 16B slots; physical slot = logical ^ (row&7); source
  // pre-swizzled so LDS dest is linear (dest = half_base + issue*8192 + tid*16).
  const int srow = tid >> 3;                       // 0..63
  const int sswz = (tid & 7) ^ (srow & 7);         // logical source slot
  // A half g, issue i covers global row m0 + i*128 + g*64 + srow.
  const u16* aRow = Xb + (size_t)(m0 + srow) * Kt + sswz * 8;
  // B half p (fnp strips), issue i: row n0 + (i*2 + srow/32)*64 + p*32 + (srow&31).
  const u16* bRow = Wb + (size_t)(n0 + (srow >> 5) * 64 + (srow & 31)) * Kt + sswz * 8;
  const int ldst = tid * 16;

  // ---- fragment-read constants ----
  // af[fm'][kk]: row_local = wm*64 + fm'*16 + frow in half g; byte in row:
  // slot = (kk*4+fk) ^ (row&7), row&7 == lane&7.
  const int frow = lane & 15;
  const int fk   = lane >> 4;                 // 0..3
  const int s0o  = ((fk ^ (lane & 7)) << 4);        // kk=0 slot byte
  const int s1o  = (((4 + fk) ^ (lane & 7)) << 4);  // kk=1 slot byte
  const int aRdC = (wm * 64 + frow) * 128;
  const int bRdC = (wn * 32 + frow) * 128;

  f32x4 acc[8][4];
  #pragma unroll
  for (int i = 0; i < 8; ++i)
    #pragma unroll
    for (int j = 0; j < 4; ++j) acc[i][j] = f32x4{0.f, 0.f, 0.f, 0.f};

  #define GATE(n) asm volatile("s_waitcnt vmcnt(" #n ")" ::: "memory")
  #define BARR()  asm volatile("s_barrier" ::: "memory")

  // Stage half-tile (2 global_load_lds per thread). kt = K-tile index.
  #define STAGE_A(g, buf, kt)                                                  \
    do {                                                                       \
      unsigned char* d_ = smem + (buf) * 32768 + (g) * 16384 + ldst;           \
      const u16* s_ = aRow + (size_t)((g) * 64) * Kt + (kt) * 64;              \
      async16(s_, d_);                                                         \
      async16(s_ + (size_t)128 * Kt, d_ + 8192);                               \
    } while (0)
  #define STAGE_B(p, buf, kt)                                                  \
    do {                                                                       \
      unsigned char* d_ = smem + 65536 + (buf) * 32768 + (p) * 16384 + ldst;   \
      const u16* s_ = bRow + (size_t)((p) * 32) * Kt + (kt) * 64;              \
      async16(s_, d_);                                                         \
      async16(s_ + (size_t)128 * Kt, d_ + 8192);                               \
    } while (0)

  // LDS fragment reads (compile-time indices -> registers).
  #define LD_A(dst, g, buf)                                                    \
    do {                                                                       \
      const unsigned char* b_ = smem + (buf) * 32768 + (g) * 16384 + aRdC;     \
      _Pragma("unroll")                                                        \
      for (int q_ = 0; q_ < 4; ++q_) {                                         \
        dst[q_][0] = *(const bf16x8*)(b_ + q_ * 2048 + s0o);                   \
        dst[q_][1] = *(const bf16x8*)(b_ + q_ * 2048 + s1o);                   \
      }                                                                        \
    } while (0)
  #define LD_B(dst, p, buf)                                                    \
    do {                                                                       \
      const unsigned char* b_ =                                                \
          smem + 65536 + (buf) * 32768 + (p) * 16384 + bRdC;                   \
      _Pragma("unroll")                                                        \
      for (int q_ = 0; q_ < 2; ++q_) {                                         \
        dst[q_][0] = *(const bf16x8*)(b_ + q_ * 2048 + s0o);                   \
        dst[q_][1] = *(const bf16x8*)(b_ + q_ * 2048 + s1o);                   \
      }                                                                        \
    } while (0)

  // MFMA cluster between barriers, kk OUTERMOST: consecutive MFMAs hit
  // different accumulators (dep distance 8); same-acc reuse only after the
  // full fm x fn sweep. GN >= 0 inserts the tile's vmcnt gate BEFORE the
  // closing barrier (gate->barrier->read: cross-wave safe).
  #define MM_G(FG, FNP, A_, B_, GN)                                            \
    do {                                                                       \
      BARR();                                                                  \
      __builtin_amdgcn_s_setprio(1);                                           \
      _Pragma("unroll")                                                        \
      for (int kk_ = 0; kk_ < 2; ++kk_)                                        \
        _Pragma("unroll")                                                      \
        for (int fm_ = 0; fm_ < 4; ++fm_)                                      \
          _Pragma("unroll")                                                    \
          for (int fn_ = 0; fn_ < 2; ++fn_)                                    \
            acc[(FG) * 4 + fm_][(FNP) * 2 + fn_] =                             \
                __builtin_amdgcn_mfma_f32_16x16x32_bf16(                       \
                    A_[fm_][kk_], B_[fn_][kk_],                                \
                    acc[(FG) * 4 + fm_][(FNP) * 2 + fn_], 0, 0, 0);            \
      __builtin_amdgcn_s_setprio(0);                                           \
      if ((GN) == 6) { asm volatile("s_waitcnt vmcnt(6)" ::: "memory"); }      \
      else if ((GN) == 0) { asm volatile("s_waitcnt vmcnt(0)" ::: "memory"); } \
      BARR();                                                                  \
    } while (0)

  // One K-tile (4 phases). BUF is a literal; all LDS addrs fold to immediates.
  #define TILE(BUF, T, GN_LAST)                                                \
    do {                                                                       \
      LD_A(af, 0, BUF);                                                        \
      LD_B(b0, 0, BUF);                                                        \
      STAGE_A(1, BUF ^ 1, (T) + 1);                                            \
      MM_G(0, 0, af, b0, -1);                                                  \
      LD_B(b1, 1, BUF);                                                        \
      STAGE_A(0, BUF, (T) + 2);                                                \
      MM_G(0, 1, af, b1, -1);                                                  \
      LD_A(af, 1, BUF);                                                        \
      STAGE_B(0, BUF, (T) + 2);                                                \
      MM_G(1, 0, af, b0, -1);                                                  \
      STAGE_B(1, BUF, (T) + 2);                                                \
      MM_G(1, 1, af, b1, GN_LAST);                                             \
    } while (0)

  bf16x8 af[4][2], b0[2][2], b1[2][2];

  // Prologue: 7 half-tiles (14 loads): tile0 full set + tile1 minus A1.
  STAGE_A(0, 0, 0);   // A0(0)
  STAGE_B(0, 0, 0);   // B0(0)
  STAGE_B(1, 0, 0);   // B1(0)
  STAGE_A(1, 0, 0);   // A1(0)
  STAGE_A(0, 1, 1);   // A0(1)
  STAGE_B(0, 1, 1);   // B0(1)
  STAGE_B(1, 1, 1);   // B1(1)
  GATE(6);            // tile 0 fully landed (newest 6 = A0/B0/B1 of tile 1)
  BARR();             // ...visible to ALL waves' ds_reads

  // Steady loop: tiles 0..61 as 31 x (2 K-tiles). Stage calendar per tile:
  // ph0->A1(t+1), ph1->A0(t+2), ph2->B0(t+2), ph3->B1(t+2); GATE(6) at tile end.
  #pragma unroll 1
  for (int t0 = 0; t0 < NKT - 2; t0 += 2) {
    TILE(0, t0, 6);
    TILE(1, t0 + 1, 6);
  }

  // Peeled t = 62 (buf 0): only A1(63) stage remains; drain fully at tile end.
  {
    LD_A(af, 0, 0);
    LD_B(b0, 0, 0);
    STAGE_A(1, 1, 63);
    MM_G(0, 0, af, b0, -1);
    LD_B(b1, 1, 0);
    MM_G(0, 1, af, b1, -1);
    LD_A(af, 1, 0);
    MM_G(1, 0, af, b0, -1);
    MM_G(1, 1, af, b1, 0);   // GATE(0): tile 63 fully landed before barrier
  }
  // Peeled t = 63 (buf 1): no stages, no gates.
  {
    LD_A(af, 0, 1);
    LD_B(b0, 0, 1);
    MM_G(0, 0, af, b0, -1);
    LD_B(b1, 1, 1);
    MM_G(0, 1, af, b1, -1);
    LD_A(af, 1, 1);
    MM_G(1, 0, af, b0, -1);
    MM_G(1, 1, af, b1, -1);
  }

  #undef GATE
  #undef BARR
  #undef STAGE_A
  #undef STAGE_B
  #undef LD_A
  #undef LD_B
  #undef MM_G
  #undef TILE

  // Epilogue: C/D mapping col = lane&15, row = (lane>>4)*4 + reg (m89/m91).
  #pragma unroll
  for (int fm = 0; fm < 8; ++fm) {
    #pragma unroll
    for (int r = 0; r < 4; ++r) {
      const size_t mrow = (size_t)(m0 + wm * 128 + fm * 16 + fk * 4 + r) * Nt;
      #pragma unroll
      for (int fn = 0; fn < 4; ++fn) {
        Y[mrow + (size_t)(n0 + wn * 64 + fn * 16 + frow)] = acc[fm][fn][r];
      }
    }
  }
}

// ---- fallback: fused single-buffer kernel (round-3 verified algebra) ----
__global__ __launch_bounds__(512) void gemm_fused(
    const float* __restrict__ Xf, const int* __restrict__ W,
    const float* __restrict__ S, float* __restrict__ Y) {
  constexpr int FBN = 128;
  constexpr int FNB = Nt / FBN;   // 86
  constexpr int FBK = 64;
  constexpr int FNKT = Kt / FBK;
  __shared__ __align__(16) unsigned char Alds[BM * FBK * 2];
  __shared__ __align__(16) unsigned char Blds[FBN * FBK * 2];

  const int tid = (int)threadIdx.x;
  const int lane = tid & 63;
  const int wid = tid >> 6;
  const int wm = wid >> 1;
  const int wn = wid & 1;

  const int bid = (int)blockIdx.x;
  const int fgrid = (Mt / BM) * FNB;
  const int wg = (bid & 7) * (fgrid / 8) + (bid >> 3);
  const int mb = wg / FNB;
  const int nb = wg - mb * FNB;
  const int m0 = mb * BM;
  const int n0 = nb * FBN;

  const int frow = lane & 15;
  const int fk = lane >> 4;
  const int fswz = (lane & 7) << 4;
  const unsigned char* aRd = Alds + (wm * 64 + frow) * 128;
  const unsigned char* bRd = Blds + (wn * 64 + frow) * 128;

  f32x4 acc[4][4];
  #pragma unroll
  for (int i = 0; i < 4; ++i)
    #pragma unroll
    for (int j = 0; j < 4; ++j) acc[i][j] = f32x4{0.f, 0.f, 0.f, 0.f};

  const int arow = tid >> 3, acol = tid & 7;
  const float* fA = Xf + (size_t)(m0 + arow) * Kt + acol * 8;
  unsigned char* fAD = Alds + arow * 128 + ((acol ^ (arow & 7)) << 4);
  const int nloc = tid >> 3, c4 = tid & 7;
  const int* fB0 = W + (size_t)(n0 + nloc) * KP + c4 * 4;
  const int* fB1 = fB0 + (size_t)64 * KP;
  const float* sp0 = S + (size_t)(n0 + nloc) * NG;
  const float* sp1 = sp0 + (size_t)64 * NG;
  unsigned char* fBD0 = Blds + nloc * 128 + ((c4 ^ (nloc & 7)) << 4);
  unsigned char* fBD1 = fBD0 + 64 * 128;

  #pragma unroll 1
  for (int kt = 0; kt < FNKT; ++kt) {
    const int k0 = kt * FBK;
    #pragma unroll
    for (int p = 0; p < 4; ++p) {
      float4 x0 = *(const float4*)(fA + (size_t)p * 64 * Kt + k0);
      float4 x1 = *(const float4*)(fA + (size_t)p * 64 * Kt + k0 + 4);
      u32x4 q;
      q[0] = pk2bf(x0.x, x0.y); q[1] = pk2bf(x0.z, x0.w);
      q[2] = pk2bf(x1.x, x1.y); q[3] = pk2bf(x1.z, x1.w);
      *(u32x4*)(fAD + p * 64 * 128) = q;
    }
    const int g = k0 >> 7;
    const float s0 = sp0[g], s1 = sp1[g];
    const float c0 = -8.f * s0, c1 = -8.f * s1;
    const int4 w0 = *(const int4*)(fB0 + (k0 >> 1));
    const int4 w1 = *(const int4*)(fB1 + (k0 >> 1));
    u32x4 q0, q1;
    q0[0] = dqpair((u32)w0.x, s0, c0); q0[1] = dqpair((u32)w0.y, s0, c0);
    q0[2] = dqpair((u32)w0.z, s0, c0); q0[3] = dqpair((u32)w0.w, s0, c0);
    q1[0] = dqpair((u32)w1.x, s1, c1); q1[1] = dqpair((u32)w1.y, s1, c1);
    q1[2] = dqpair((u32)w1.z, s1, c1); q1[3] = dqpair((u32)w1.w, s1, c1);
    *(u32x4*)fBD0 = q0;
    *(u32x4*)fBD1 = q1;

    __syncthreads();

    #pragma unroll
    for (int kk = 0; kk < 2; ++kk) {
      const int koff = (kk * 64 + fk * 16) ^ fswz;
      bf16x8 af[4], bfr[4];
      #pragma unroll
      for (int fm = 0; fm < 4; ++fm)
        af[fm] = *(const bf16x8*)(aRd + fm * 16 * 128 + koff);
      #pragma unroll
      for (int fn = 0; fn < 4; ++fn)
        bfr[fn] = *(const bf16x8*)(bRd + fn * 16 * 128 + koff);
      #pragma unroll
      for (int fm = 0; fm < 4; ++fm)
        #pragma unroll
        for (int fn = 0; fn < 4; ++fn)
          acc[fm][fn] = __builtin_amdgcn_mfma_f32_16x16x32_bf16(
              af[fm], bfr[fn], acc[fm][fn], 0, 0, 0);
    }
    __syncthreads();
  }

  #pragma unroll
  for (int fm = 0; fm < 4; ++fm) {
    #pragma unroll
    for (int r = 0; r < 4; ++r) {
      const size_t mrow = (size_t)(m0 + wm * 64 + fm * 16 + fk * 4 + r) * Nt;
      #pragma unroll
      for (int fn = 0; fn < 4; ++fn)
        Y[mrow + (size_t)(n0 + wn * 64 + fn * 16 + frow)] = acc[fm][fn][r];
    }
  }
}

}  // namespace

extern "C" void kernel_launch(void* const* d_in, const int* in_sizes, int n_in,
                              void* d_out, int out_size, void* d_ws, size_t ws_size,
                              hipStream_t stream) {
  (void)in_sizes; (void)n_in; (void)out_size;
  const float* X = (const float*)d_in[0];
  const int* W   = (const int*)d_in[1];
  const float* S = (const float*)d_in[2];
  float* Y       = (float*)d_out;

  const size_t xbytes = (size_t)Mt * Kt * 2;   // 64 MiB
  const size_t wbytes = (size_t)Nt * Kt * 2;   // 86 MiB

  if (ws_size >= xbytes + wbytes) {
    u16* Xb = (u16*)d_ws;
    u16* Wb = (u16*)((char*)d_ws + xbytes);
    cvt_x<<<dim3(2048), dim3(256), 0, stream>>>(X, (u32*)Xb);
    cvt_w<<<dim3(2048), dim3(256), 0, stream>>>(W, S, (u32*)Wb);
    gemm8p<<<dim3(GRID), dim3(THREADS), 0, stream>>>(Xb, Wb, Y);
  } else {
    gemm_fused<<<dim3((Mt / BM) * (Nt / 128)), dim3(512), 0, stream>>>(X, W, S, Y);
  }
}